// Round 1
// baseline (77.101 us; speedup 1.0000x reference)
//
#include <hip/hip_runtime.h>
#include <math.h>

// S4D SSM kernel materialization:
//   K[h,l] = 2 * Re( sum_n CB[h,n] * exp(dtA[h,n] * l) ) + D[h]*(l==0)
//
// R5 strategy (occupancy-first; assumes L = 1024, N = 64):
//  - block = 512 (8 waves), one h per block. Wave w owns state-quarter
//    q = w&3 (8 states = 4 even pairs, <2 x float> SoA) and l-half
//    hl = w>>2. Each lane owns T=8 consecutive l values.
//  - acc shrinks to 8 v2f = 16 VGPRs (was 32 at T=16); rotation chain is
//    7 dependent steps (was 15). __launch_bounds__(512,8) forces <=64
//    VGPRs -> 8 waves/SIMD (32/CU), 4 blocks/CU. Total waves = 8192 =
//    exactly one full device residency: no tail, 2x latency hiding vs R4.
//  - Trans cost per thread unchanged (8 pairs x 6 trans); inner VALU work
//    per thread halves.
//  - Partials: s_part[q][hl*512 + t*64 + lane] -- writes lane-consecutive
//    (conflict-free). One-shot reduction: 512 threads x 2 l each, 4-way
//    read conflict only (negligible), float2 coalesced store.
//  - Final *2 folded into CB at setup.

#define NSTATE 64
#define TCHUNK 8

typedef float v2f __attribute__((ext_vector_type(2)));

__global__ __launch_bounds__(512, 8) void ssk_diag_kernel(
    const float* __restrict__ log_dt,   // (H,)
    const float* __restrict__ Lre,      // (H,N)
    const float* __restrict__ Lim,      // (H,N)
    const float* __restrict__ Bv,       // (H,N,1)
    const float* __restrict__ Cre,      // (H,1,N)
    const float* __restrict__ Cim,      // (H,1,N)
    const float* __restrict__ Dv,       // (H,)
    float* __restrict__ K,              // (H,L)
    int L)
{
    const int h   = blockIdx.x;
    const int tid = threadIdx.x;

    // SoA so even-n pairs are contiguous for v2f loads
    __shared__ float s_are[NSTATE], s_aim[NSTATE];
    __shared__ float s_str[NSTATE], s_sti[NSTATE];   // step = exp(dtA)
    __shared__ float s_cbr[NSTATE], s_cbi[NSTATE];   // 2*CB
    __shared__ float s_part[4 * 1024];               // per-quarter partials, 16 KB

    if (tid < NSTATE) {
        const int n   = tid;
        const int idx = h * NSTATE + n;
        const float dt  = expf(log_dt[h]);
        const float lre = Lre[idx];
        const float lim = Lim[idx];
        const float are = dt * lre;
        const float aim = dt * lim;

        // Stable complex expm1: exp(are+i*aim) - 1
        float sy, cy;
        sincosf(aim, &sy, &cy);
        const float sh    = sinf(0.5f * aim);
        const float em_re = expm1f(are) * cy - 2.0f * sh * sh;
        const float em_im = expf(are) * sy;

        // B_bar = em / Lambda * B
        const float inv_d = 1.0f / (lre * lre + lim * lim);
        const float b     = Bv[idx];
        const float bb_re = (em_re * lre + em_im * lim) * inv_d * b;
        const float bb_im = (em_im * lre - em_re * lim) * inv_d * b;

        // 2*CB = 2 * (Cre + i*Cim) * B_bar   (fold the final *2 in here)
        const float cre = Cre[idx];
        const float cim = Cim[idx];
        s_cbr[n] = 2.0f * (cre * bb_re - cim * bb_im);
        s_cbi[n] = 2.0f * (cre * bb_im + cim * bb_re);
        s_are[n] = are;
        s_aim[n] = aim;
        s_str[n] = em_re + 1.0f;   // exp(dtA) = expm1(dtA) + 1
        s_sti[n] = em_im;
    }
    __syncthreads();

    const int wave = tid >> 6;
    const int lane = tid & 63;
    const int q    = wave & 3;      // state quarter: states [16q, 16q+16)
    const int hl   = wave >> 2;     // l half: l in [512*hl, 512*hl+512)
    const int l0   = (hl << 9) + lane * TCHUNK;
    const float fl = (float)l0;

    v2f acc[TCHUNK];
    #pragma unroll
    for (int t = 0; t < TCHUNK; ++t) acc[t] = (v2f){0.0f, 0.0f};

    const int nb = q << 4;   // this wave's 16 states = 8 even pairs
    #pragma unroll 2
    for (int p = 0; p < 8; ++p) {
        const int n = nb + 2 * p;
        const v2f ar  = *(const v2f*)&s_are[n];
        const v2f ai  = *(const v2f*)&s_aim[n];
        const v2f str_= *(const v2f*)&s_str[n];
        const v2f sti = *(const v2f*)&s_sti[n];
        const v2f cbr = *(const v2f*)&s_cbr[n];
        const v2f cbi = *(const v2f*)&s_cbi[n];

        // z0 = exp(dtA * l0)
        const v2f argr = ar * fl;
        const v2f argi = ai * fl;
        const float m0 = __expf(argr.x);
        const float m1 = __expf(argr.y);
        float s0, c0, s1, c1;
        __sincosf(argi.x, &s0, &c0);
        __sincosf(argi.y, &s1, &c1);
        const v2f zr = {m0 * c0, m1 * c1};
        const v2f zi = {m0 * s0, m1 * s1};

        // w = (2*CB) * z0
        v2f wr = cbr * zr - cbi * zi;
        v2f wi = cbr * zi + cbi * zr;

        #pragma unroll
        for (int t = 0; t < TCHUNK; ++t) {
            acc[t] += wr;
            if (t < TCHUNK - 1) {
                const v2f nr = wr * str_ - wi * sti;
                wi = wr * sti + wi * str_;
                wr = nr;
            }
        }
    }

    // Write per-(quarter, half) partials, interleaved:
    // s_part[q*1024 + hl*512 + t*64 + lane] -- lane-consecutive, conflict-free.
    {
        float* base = &s_part[(q << 10) + (hl << 9)];
        #pragma unroll
        for (int t = 0; t < TCHUNK; ++t)
            base[(t << 6) + lane] = acc[t].x + acc[t].y;
    }
    __syncthreads();

    // Reduce 4 state-quarters; thread tid produces l = 2*tid, 2*tid+1.
    // Inverse of the interleave: for l, hl=l>>9, t=l&7, lane_src=(l&511)>>3
    //   pos = hl*512 + t*64 + lane_src
    const int l = tid << 1;
    float2 o;
    #pragma unroll
    for (int k2 = 0; k2 < 2; ++k2) {
        const int lk  = l + k2;
        const int pos = ((lk >> 9) << 9) | ((lk & 7) << 6) | ((lk & 511) >> 3);
        (&o.x)[k2] = s_part[pos] + s_part[1024 + pos] +
                     s_part[2048 + pos] + s_part[3072 + pos];
    }
    if (tid == 0) o.x += Dv[h];
    *(float2*)(K + h * L + l) = o;
}

extern "C" void kernel_launch(void* const* d_in, const int* in_sizes, int n_in,
                              void* d_out, int out_size, void* d_ws, size_t ws_size,
                              hipStream_t stream) {
    const float* log_dt = (const float*)d_in[0];
    const float* Lre    = (const float*)d_in[1];
    const float* Lim    = (const float*)d_in[2];
    const float* B      = (const float*)d_in[3];
    const float* Cre    = (const float*)d_in[4];
    const float* Cim    = (const float*)d_in[5];
    const float* D      = (const float*)d_in[6];
    const int H = in_sizes[0];
    const int L = out_size / H;   // 1024 per problem spec (kernel assumes this)
    float* K = (float*)d_out;

    ssk_diag_kernel<<<H, 512, 0, stream>>>(log_dt, Lre, Lim, B, Cre, Cim, D, K, L);
}